// Round 17
// baseline (979.733 us; speedup 1.0000x reference)
//
#include <hip/hip_runtime.h>

typedef __attribute__((ext_vector_type(4)))  int int4v;
typedef __attribute__((ext_vector_type(16))) int i32x16;

union B16 { int4v v; signed char c[16]; };

// ---------- helpers ----------
__device__ __forceinline__ float rcp_(float x){ return __builtin_amdgcn_rcpf(x); }
__device__ __forceinline__ float sigm(float x){ return rcp_(1.f + __expf(-x)); }
__device__ __forceinline__ float tanh_(float x){
  float e = __expf(-2.f * fabsf(x));        // overflow-safe
  float r = (1.f - e) * rcp_(1.f + e);
  return copysignf(r, x);
}
// h in (-1,1): h*2^15 = a1*256 + (a0 + 128), |err| <= 2^-16
__device__ __forceinline__ void h_limbs(float h, int& a1, int& a0){
  float f1 = floorf(h * 128.f);
  f1 = fminf(fmaxf(f1, -128.f), 127.f);
  float r = fmaf(h, 32768.f, f1 * -256.f) - 128.f;   // in [-128,128)
  float f0 = fminf(rintf(r), 127.f);
  a1 = (int)f1; a0 = (int)f0;
}

// 16B LLC-coherent load (sc0+sc1: same bypass semantics as agent-scope atomics;
// legal because every byte read is flag-ordered).
__device__ __forceinline__ void issue_l128_cc(const void* p, int4v& d){
  asm volatile("global_load_dwordx4 %0, %1, off sc0 sc1" : "=&v"(d) : "v"(p) : "memory");
}

// ---------- kernel 1: G_in = emb @ w_ih.T + b_ih + b_hh (fp32); h0 -> i8 limb planes ----------
__global__ __launch_bounds__(256) void prep_kernel(
    const float* __restrict__ emb, const float* __restrict__ w_ih,
    const float* __restrict__ b_ih, const float* __restrict__ b_hh,
    const float* __restrict__ h0, float* __restrict__ G_in,
    char* __restrict__ a1buf, char* __restrict__ a0buf)
{
  __shared__ __align__(16) float wt[16 * 512];
  const int tid = threadIdx.x;
  const int colbase = blockIdx.x << 4;       // 16 gate-cols per block
  #pragma unroll
  for (int i = 0; i < 8; ++i){
    int f = tid + (i << 8);                  // 2048 float4 granules
    int r = f >> 7, q = (f & 127) << 2;
    *(float4*)&wt[(r << 9) + q] = *(const float4*)&w_ih[((size_t)(colbase + r) << 9) + q];
  }
  __syncthreads();
  const int v_ = tid & 127, ch = tid >> 7;
  float acc[8] = {0,0,0,0,0,0,0,0};
  const float* ep = emb + ((size_t)v_ << 9);
  for (int kq = 0; kq < 128; ++kq){
    float4 e = *(const float4*)(ep + (kq << 2));
    #pragma unroll
    for (int c = 0; c < 8; ++c){
      float4 w = *(const float4*)&wt[(((ch << 3) + c) << 9) + (kq << 2)]; // LDS broadcast
      acc[c] += e.x * w.x + e.y * w.y + e.z * w.z + e.w * w.w;
    }
  }
  const int col0 = colbase + (ch << 3);
  #pragma unroll
  for (int c = 0; c < 8; ++c) acc[c] += b_ih[col0 + c] + b_hh[col0 + c];
  float* gp = &G_in[((size_t)v_ << 12) + col0];
  float4 r0 = {acc[0], acc[1], acc[2], acc[3]};
  float4 r1 = {acc[4], acc[5], acc[6], acc[7]};
  *(float4*)gp = r0;
  *(float4*)(gp + 4) = r1;

  // h0 -> limb planes, buffer 0
  int g0 = (blockIdx.x << 10) + (tid << 2);
  float4 hv = *(const float4*)&h0[g0];
  int a1x,a0x,a1y,a0y,a1z,a0z,a1w,a0w;
  h_limbs(hv.x, a1x, a0x); h_limbs(hv.y, a1y, a0y);
  h_limbs(hv.z, a1z, a0z); h_limbs(hv.w, a1w, a0w);
  unsigned u1 = (unsigned)(a1x & 255) | ((unsigned)(a1y & 255) << 8)
              | ((unsigned)(a1z & 255) << 16) | ((unsigned)(a1w & 255) << 24);
  unsigned u0 = (unsigned)(a0x & 255) | ((unsigned)(a0y & 255) << 8)
              | ((unsigned)(a0z & 255) << 16) | ((unsigned)(a0w & 255) << 24);
  ((unsigned*)a1buf)[g0 >> 2] = u1;
  ((unsigned*)a0buf)[g0 >> 2] = u0;
}

// ---------- kernel 2: persistent LSTM, exact i8-limb fixed-point recurrent GEMM ----------
// Round-16: DECOUPLED halves. half h (waves 4h..4h+3) owns contiguous K range
// ks [16h,16h+16) == producers [16h,16h+16). Each half: own poll (1 wave), own
// 32KB stage region, own LDS-counter half-barrier (4 waves). Block-wide sync
// only at gate-join and publish. Proven agent-scope sc0+sc1 protocol unchanged.
__global__ __launch_bounds__(512, 1) void lstm_kernel(
    const int* __restrict__ input, const float* __restrict__ c0,
    const float* __restrict__ w_hh, const float* __restrict__ w_out,
    const float* __restrict__ b_out, const float* __restrict__ G_in,
    char* __restrict__ a1base, char* __restrict__ a0base,
    unsigned* __restrict__ flags, float* __restrict__ out)
{
  const int tid  = threadIdx.x;
  const int lane = tid & 63;
  const int wid  = tid >> 6;                 // 0..7
  const int gate = wid & 3;
  const int half = wid >> 2;                 // K-half: h -> ks [16h, 16h+16)
  const int bg   = blockIdx.x >> 5;          // 0..7
  const int cg   = blockIdx.x & 31;          // 0..31
  const int row  = tid & 31;                 // staging row
  const int grp8 = (tid >> 5) & 7;           // staging granule group within half, 0..7

  __shared__ __align__(16) unsigned long long sA1[4096]; // 32 KB: full a1 slab, A-frag order
  __shared__ __align__(16) unsigned long long sA0[4096]; // 32 KB: full a0 slab
  __shared__ __align__(16) float sGa[32 * 132];          // gates partial, half 0
  __shared__ __align__(16) float sGb[32 * 132];          // gates partial, half 1
  __shared__ float sKc2[2][128];                         // per-col 128-offset bias, per half
  __shared__ unsigned hbar[2];                           // half-barrier counters

  if (tid < 2) hbar[tid] = 0;

  // ---- W_hh -> i8 limbs in registers (this wave's contiguous 16 K-steps) ----
  int4v b1f[16], b0f[16];
  {
    const float* wrow = w_hh + (size_t)(gate * 1024 + cg * 32 + (lane & 31)) * 1024;
    const int kb0 = (lane >> 5) << 4;
    float csum = 0.f;
    #pragma unroll
    for (int j = 0; j < 16; ++j){
      const int gks = (half << 4) + j;       // contiguous K
      B16 v1, v0;
      #pragma unroll
      for (int q = 0; q < 4; ++q){
        float4 w4 = *(const float4*)&wrow[gks * 32 + kb0 + (q << 2)];
        float wa[4] = {w4.x, w4.y, w4.z, w4.w};
        #pragma unroll
        for (int jj = 0; jj < 4; ++jj){
          float w = wa[jj];
          csum += w;
          float s1 = rintf(w * 2048.f);                           // W*2^11
          float s0 = fminf(rintf(fmaf(w, 524288.f, s1 * -256.f)), 127.f);
          v1.c[(q << 2) + jj] = (signed char)(int)s1;
          v0.c[(q << 2) + jj] = (signed char)(int)s0;
        }
      }
      b1f[j] = v1.v; b0f[j] = v0.v;
    }
    csum += __shfl_xor(csum, 32, 64);        // per-col partial over this wave's K=512
    if (lane < 32) sKc2[half][(gate << 5) + lane] = csum * 0.00390625f; // 128*2^-15*colsum
  }
  __syncthreads();                           // hbar + sKc2 visible

  // cell-update ownership: ALL 512 threads, thread owns (batch bl, 2 units u2)
  const int bl = tid >> 4;                   // 0..31
  const int u2 = (tid & 15) << 1;            // 0..30
  const int b  = (bg << 5) + bl;
  float2 cr = *(const float2*)&c0[((size_t)b << 10) + (cg << 5) + u2];
  unsigned* slots = &flags[bg * 32];         // 32 x u32 = one 128B line per bg
  unsigned* myslot = &flags[bg * 32 + cg];
  const size_t rbase = (size_t)((bg << 5) + row) << 10;
  unsigned hgen = 0;                         // half-barrier generation

  // half-barrier: monotonic 4-wave counter; guard-capped (wrong-but-terminates)
  #define HALFBAR() do { \
    asm volatile("s_waitcnt lgkmcnt(0)" ::: "memory"); \
    if (lane == 0) __hip_atomic_fetch_add(&hbar[half], 1u, __ATOMIC_RELAXED, __HIP_MEMORY_SCOPE_WORKGROUP); \
    ++hgen; \
    int g_ = 0; \
    while (__hip_atomic_load(&hbar[half], __ATOMIC_RELAXED, __HIP_MEMORY_SCOPE_WORKGROUP) < 4u*hgen) { \
      if (++g_ > (1 << 20)) break; } \
    __builtin_amdgcn_sched_barrier(0); \
  } while(0)

  #pragma unroll 1
  for (int t = 0; t < 128; ++t){
    const char* s1b = a1base + (size_t)(t & 1) * 262144;
    const char* s0b = a0base + (size_t)(t & 1) * 262144;
    char* d1b = a1base + (size_t)((t + 1) & 1) * 262144;
    char* d0b = a0base + (size_t)((t + 1) & 1) * 262144;
    const unsigned target = (unsigned)t;

    // input-side gates (all threads; 2 units each) — no h dependency, issue early
    int iv = input[t * 256 + b];
    const float* gp = G_in + ((size_t)iv << 12) + (cg << 5) + u2;
    float2 q0 = *(const float2*)(gp);
    float2 q1 = *(const float2*)(gp + 1024);
    float2 q2 = *(const float2*)(gp + 2048);
    float2 q3 = *(const float2*)(gp + 3072);

    // ---- per-half poll: leader wave polls ONLY this half's 16 producers ----
    if (target){
      if (wid == 0){                         // half0: producers 0..15
        int guard = 0;
        for (;;){
          unsigned v = (lane < 32)
            ? __hip_atomic_load(&slots[lane], __ATOMIC_RELAXED, __HIP_MEMORY_SCOPE_AGENT)
            : 0xFFFFFFFFu;
          if (__ballot(lane >= 16 || v >= target) == ~0ull) break;
          if (++guard > (1 << 20)) break;
        }
      } else if (wid == 4){                  // half1: producers 16..31
        int guard = 0;
        for (;;){
          unsigned v = (lane < 32)
            ? __hip_atomic_load(&slots[lane], __ATOMIC_RELAXED, __HIP_MEMORY_SCOPE_AGENT)
            : 0xFFFFFFFFu;
          if (__ballot(lane < 16 || lane >= 32 || v >= target) == ~0ull) break;
          if (++guard > (1 << 20)) break;
        }
      }
    }
    HALFBAR();                               // crossing 1: this half's producers ready

    // ---- issue this half's 8 slab loads (granules m = 32h + grp8 + 8i) ----
    int4v gv1[4], gv0[4];
    #pragma unroll
    for (int i = 0; i < 4; ++i){
      const int m = (half << 5) + grp8 + (i << 3);
      size_t off = rbase + ((size_t)m << 4);
      issue_l128_cc(s1b + off, gv1[i]);
      issue_l128_cc(s0b + off, gv0[i]);
    }

    i32x16 acc_hi = {}, acc_m1 = {}, acc_m2 = {};
    const int4v* A1 = (const int4v*)sA1;
    const int4v* A0 = (const int4v*)sA0;

    // ---- sub-chunk A: granules i=0,1 (ks 16h..16h+7) ----
    asm volatile("s_waitcnt vmcnt(4)" ::: "memory"); // 5 older (input+G_in) + first 4 slab done
    __builtin_amdgcn_sched_barrier(0);
    #pragma unroll
    for (int i = 0; i < 2; ++i){
      const int m = (half << 5) + grp8 + (i << 3);
      const int lidx = ((((m >> 1) << 6) + ((m & 1) << 5) + row)) << 1; // ull units
      *(int4v*)&sA1[lidx] = gv1[i];
      *(int4v*)&sA0[lidx] = gv0[i];
    }
    HALFBAR();                               // crossing 2: sub-A staged by this half
    #pragma unroll
    for (int j = 0; j < 8; ++j){
      const int ks = (half << 4) + j;
      int4v af1 = A1[(ks << 6) + lane];
      acc_hi = __builtin_amdgcn_mfma_i32_32x32x32_i8(af1, b1f[j], acc_hi, 0, 0, 0);
      acc_m1 = __builtin_amdgcn_mfma_i32_32x32x32_i8(af1, b0f[j], acc_m1, 0, 0, 0);
      int4v af0 = A0[(ks << 6) + lane];
      acc_m2 = __builtin_amdgcn_mfma_i32_32x32x32_i8(af0, b1f[j], acc_m2, 0, 0, 0);
    }

    // ---- sub-chunk B: granules i=2,3 (ks 16h+8..16h+15) ----
    asm volatile("s_waitcnt vmcnt(0)" ::: "memory");
    __builtin_amdgcn_sched_barrier(0);
    #pragma unroll
    for (int i = 2; i < 4; ++i){
      const int m = (half << 5) + grp8 + (i << 3);
      const int lidx = ((((m >> 1) << 6) + ((m & 1) << 5) + row)) << 1;
      *(int4v*)&sA1[lidx] = gv1[i];
      *(int4v*)&sA0[lidx] = gv0[i];
    }
    HALFBAR();                               // crossing 3: sub-B staged
    #pragma unroll
    for (int j = 8; j < 16; ++j){
      const int ks = (half << 4) + j;
      int4v af1 = A1[(ks << 6) + lane];
      acc_hi = __builtin_amdgcn_mfma_i32_32x32x32_i8(af1, b1f[j], acc_hi, 0, 0, 0);
      acc_m1 = __builtin_amdgcn_mfma_i32_32x32x32_i8(af1, b0f[j], acc_m1, 0, 0, 0);
      int4v af0 = A0[(ks << 6) + lane];
      acc_m2 = __builtin_amdgcn_mfma_i32_32x32x32_i8(af0, b1f[j], acc_m2, 0, 0, 0);
    }

    // combine limb accs -> fp32 partial gates into this half's buffer
    // C-layout: col=lane&31, row=(r&3)+8*(r>>2)+4*(lane>>5)
    {
      float* sGh = half ? sGb : sGa;
      const int col = (gate << 5) + (lane & 31);
      const int rb  = (lane >> 5) << 2;
      #pragma unroll
      for (int r = 0; r < 16; ++r){
        int rrow = (r & 3) + ((r >> 2) << 3) + rb;
        sGh[rrow * 132 + col] = 3.814697265625e-06f     * (float)acc_hi[r]             // 2^-18
                              + 1.4901161193847656e-08f * (float)(acc_m1[r] + acc_m2[r]); // 2^-26
      }
    }
    __syncthreads();                         // JOIN: both halves' partials visible

    // elementwise LSTM cell update (ALL threads; thread owns (b, 2 units))
    {
      float2 kI = {sKc2[0][ 0 + u2] + sKc2[1][ 0 + u2], sKc2[0][ 1 + u2] + sKc2[1][ 1 + u2]};
      float2 kF = {sKc2[0][32 + u2] + sKc2[1][32 + u2], sKc2[0][33 + u2] + sKc2[1][33 + u2]};
      float2 kG = {sKc2[0][64 + u2] + sKc2[1][64 + u2], sKc2[0][65 + u2] + sKc2[1][65 + u2]};
      float2 kO = {sKc2[0][96 + u2] + sKc2[1][96 + u2], sKc2[0][97 + u2] + sKc2[1][97 + u2]};
      const float* ga = &sGa[bl * 132];
      const float* gb = &sGb[bl * 132];
      float2 gI = {ga[ 0 + u2] + gb[ 0 + u2], ga[ 1 + u2] + gb[ 1 + u2]};
      float2 gF = {ga[32 + u2] + gb[32 + u2], ga[33 + u2] + gb[33 + u2]};
      float2 gG = {ga[64 + u2] + gb[64 + u2], ga[65 + u2] + gb[65 + u2]};
      float2 gO = {ga[96 + u2] + gb[96 + u2], ga[97 + u2] + gb[97 + u2]};
      int a1a,a0a,a1b,a0b;
      { float I=sigm(gI.x+q0.x+kI.x), F=sigm(gF.x+q1.x+kF.x), G=tanh_(gG.x+q2.x+kG.x), O=sigm(gO.x+q3.x+kO.x);
        float Cn=F*cr.x+I*G; cr.x=Cn; h_limbs(O*tanh_(Cn), a1a, a0a); }
      { float I=sigm(gI.y+q0.y+kI.y), F=sigm(gF.y+q1.y+kF.y), G=tanh_(gG.y+q2.y+kG.y), O=sigm(gO.y+q3.y+kO.y);
        float Cn=F*cr.y+I*G; cr.y=Cn; h_limbs(O*tanh_(Cn), a1b, a0b); }
      unsigned m1 = (unsigned)(a1a & 255) | ((unsigned)(a1b & 255) << 8);
      unsigned m0 = (unsigned)(a0a & 255) | ((unsigned)(a0b & 255) << 8);
      unsigned p1 = __shfl_xor(m1, 1, 64);   // partner holds units u2+2, u2+3
      unsigned p0 = __shfl_xor(m0, 1, 64);
      if (!(tid & 1)){
        unsigned w1 = m1 | (p1 << 16);
        unsigned w0 = m0 | (p0 << 16);
        size_t eidx = (((size_t)b << 10) + (cg << 5) + u2) >> 2;
        __hip_atomic_store((unsigned*)d1b + eidx, w1, __ATOMIC_RELAXED, __HIP_MEMORY_SCOPE_AGENT);
        __hip_atomic_store((unsigned*)d0b + eidx, w0, __ATOMIC_RELAXED, __HIP_MEMORY_SCOPE_AGENT);
      }
    }
    __syncthreads();   // drains vmcnt(0): h-stores acked at LLC before the slot store below
    if (tid == 0)      // plain slot store — order via vmcnt drain
      __hip_atomic_store(myslot, (unsigned)(t + 1), __ATOMIC_RELAXED, __HIP_MEMORY_SCOPE_AGENT);
  }

  // ---- head: out[b, 2cg .. 2cg+1] = h_127 @ w_out.T + b_out (h_127 in buffer 0) ----
  if (wid == 0){
    int guard = 0;
    for (;;){
      unsigned v = (lane < 32)
        ? __hip_atomic_load(&slots[lane], __ATOMIC_RELAXED, __HIP_MEMORY_SCOPE_AGENT)
        : 0xFFFFFFFFu;
      if (__ballot(v >= 128u) == ~0ull) break;
      if (++guard > (1 << 20)) break;
    }
  }
  __syncthreads();
  if (tid < 256){
    const unsigned* h1p = (const unsigned*)a1base;
    const unsigned* h0p = (const unsigned*)a0base;
    const int hbl = (tid >> 3) & 31;
    const int hb  = (bg << 5) + hbl;
    const int ksl = tid & 7;
    const int o0 = cg << 1;
    float s0 = 0.f, s1 = 0.f;
    const float* w0p = w_out + ((size_t)o0 << 10);
    const float* w1p = w0p + 1024;
    for (int k = ksl * 128; k < ksl * 128 + 128; k += 4){
      size_t idx = (((size_t)hb << 10) + k) >> 2;
      unsigned v1 = __hip_atomic_load(h1p + idx, __ATOMIC_RELAXED, __HIP_MEMORY_SCOPE_AGENT);
      unsigned v0 = __hip_atomic_load(h0p + idx, __ATOMIC_RELAXED, __HIP_MEMORY_SCOPE_AGENT);
      float4 w0 = *(const float4*)(w0p + k);
      float4 w1 = *(const float4*)(w1p + k);
      float hh[4];
      #pragma unroll
      for (int j = 0; j < 4; ++j){
        int A1j = (int)(signed char)((v1 >> (8 * j)) & 255);
        int A0j = (int)(signed char)((v0 >> (8 * j)) & 255);
        hh[j] = (float)(A1j * 256 + A0j + 128) * 3.0517578125e-05f;  // 2^-15
      }
      s0 += hh[0]*w0.x + hh[1]*w0.y + hh[2]*w0.z + hh[3]*w0.w;
      s1 += hh[0]*w1.x + hh[1]*w1.y + hh[2]*w1.z + hh[3]*w1.w;
    }
    sGa[hbl * 16 + (ksl << 1)]     = s0;
    sGa[hbl * 16 + (ksl << 1) + 1] = s1;
  }
  __syncthreads();
  if (tid < 64){
    int bl2 = tid >> 1, ol = tid & 1;
    float s = b_out[(cg << 1) + ol];
    #pragma unroll
    for (int q = 0; q < 8; ++q) s += sGa[bl2 * 16 + (q << 1) + ol];
    out[((size_t)((bg << 5) + bl2) << 6) + (cg << 1) + ol] = s;
  }
  #undef HALFBAR
}

extern "C" void kernel_launch(void* const* d_in, const int* in_sizes, int n_in,
                              void* d_out, int out_size, void* d_ws, size_t ws_size,
                              hipStream_t stream){
  (void)in_sizes; (void)n_in; (void)out_size; (void)ws_size;
  const int* input   = (const int*)d_in[0];   // harness stores integer inputs as int32
  const float* h0    = (const float*)d_in[1];
  const float* c0    = (const float*)d_in[2];
  const float* emb   = (const float*)d_in[3];
  const float* w_ih  = (const float*)d_in[4];
  const float* w_hh  = (const float*)d_in[5];
  const float* b_ih  = (const float*)d_in[6];
  const float* b_hh  = (const float*)d_in[7];
  const float* w_out = (const float*)d_in[8];
  const float* b_out = (const float*)d_in[9];
  float* out = (float*)d_out;

  char* ws = (char*)d_ws;
  float* G_in   = (float*)ws;                           // 2 MB fp32 [128][4096]
  char* a1buf   = ws + (2u << 20);                      // 512 KB: 2 x i8 plane [256][1024]
  char* a0buf   = ws + (2u << 20) + (512u << 10);       // 512 KB
  unsigned* flags = (unsigned*)(ws + (3u << 20));       // 1 KB slot array (8 bg x 32)

  hipMemsetAsync(flags, 0, 4096, stream);
  prep_kernel<<<dim3(256), dim3(256), 0, stream>>>(emb, w_ih, b_ih, b_hh, h0, G_in, a1buf, a0buf);

  void* args[] = {(void*)&input, (void*)&c0, (void*)&w_hh, (void*)&w_out, (void*)&b_out,
                  (void*)&G_in, (void*)&a1buf, (void*)&a0buf, (void*)&flags, (void*)&out};
  if (hipLaunchCooperativeKernel((void*)lstm_kernel, dim3(256), dim3(512), args, 0, stream)
      != hipSuccess){
    // fallback: 256 blocks at 1 block/CU (LDS ~100 KB caps 1/CU) are de-facto co-resident
    lstm_kernel<<<dim3(256), dim3(512), 0, stream>>>(input, c0, w_hh, w_out, b_out,
                                                     G_in, a1buf, a0buf, flags, out);
  }
}